// Round 5
// baseline (2755.650 us; speedup 1.0000x reference)
//
#include <hip/hip_runtime.h>

using bf16x8 = __attribute__((ext_vector_type(8))) short;
using f32x4  = __attribute__((ext_vector_type(4))) float;

#define MFMA16(a,b,c) __builtin_amdgcn_mfma_f32_16x16x32_bf16((a),(b),(c),0,0,0)

constexpr int BB   = 16;
constexpr int TT   = 65568;
constexpr int NF   = 4097;   // fast frames
constexpr int NS   = 1365;   // slow frames
constexpr int HOPS = 48;

// ---------- helpers ----------
__device__ __forceinline__ unsigned short f2bf(float f) {
  union { float f; unsigned u; } v; v.f = f;
  return (unsigned short)((v.u + 0x7fffu + ((v.u >> 16) & 1u)) >> 16);
}
__device__ __forceinline__ float bf2f(unsigned short h) {
  union { unsigned u; float f; } v; v.u = ((unsigned)h) << 16; return v.f;
}
__device__ __forceinline__ float fsig(float x) {
  float e = __builtin_amdgcn_exp2f(-1.4426950408889634f * x);
  return __builtin_amdgcn_rcpf(1.0f + e);
}
__device__ __forceinline__ float ftanh(float x) {
  float e = __builtin_amdgcn_exp2f(-2.8853900817779268f * x);
  return __builtin_amdgcn_rcpf(1.0f + e) * 2.0f - 1.0f;
}

// ---------- stage 1: x_proj[s][o][b] (bf16), o-bias = b_ih + (r,z gates) b_hh ----------
__global__ __launch_bounds__(256) void k_xproj(const float* __restrict__ x,
    const float* __restrict__ Wih, const float* __restrict__ bih,
    const float* __restrict__ bhh, unsigned short* __restrict__ xp) {
  extern __shared__ char smem[];
  unsigned short* wl = (unsigned short*)smem;            // [768][104] bf16, pad->no bank conflict
  for (int e4 = threadIdx.x; e4 < 768 * 96 / 4; e4 += 256) {
    int idx = e4 * 4;
    int o = idx / 96, k = idx - o * 96;                  // rows are 96 (mult of 4): float4 stays in-row
    float4 v = ((const float4*)Wih)[e4];
    ushort4 st; st.x = f2bf(v.x); st.y = f2bf(v.y); st.z = f2bf(v.z); st.w = f2bf(v.w);
    *(ushort4*)&wl[o * 104 + k] = st;
  }
  __syncthreads();
  int lane = threadIdx.x & 63;
  int s = blockIdx.x * 4 + (threadIdx.x >> 6);
  if (s >= NS) return;
  int col = lane & 15, krow = lane >> 4;
  int kh = krow * 8, b0 = krow * 4;
  bf16x8 A[3];
#pragma unroll
  for (int kk = 0; kk < 3; ++kk) {
    const float* px = x + (size_t)col * TT + s * HOPS + kk * 32 + kh;
    float4 f0 = *(const float4*)px;
    float4 f1 = *(const float4*)(px + 4);
    bf16x8 a;
    a[0] = (short)f2bf(f0.x); a[1] = (short)f2bf(f0.y);
    a[2] = (short)f2bf(f0.z); a[3] = (short)f2bf(f0.w);
    a[4] = (short)f2bf(f1.x); a[5] = (short)f2bf(f1.y);
    a[6] = (short)f2bf(f1.z); a[7] = (short)f2bf(f1.w);
    A[kk] = a;
  }
#pragma unroll 4
  for (int n = 0; n < 48; ++n) {
    f32x4 acc = {0.f, 0.f, 0.f, 0.f};
#pragma unroll
    for (int kk = 0; kk < 3; ++kk) {
      bf16x8 bw = *(const bf16x8*)&wl[(n * 16 + col) * 104 + kk * 32 + kh];
      acc = MFMA16(A[kk], bw, acc);
    }
    int o = n * 16 + col;
    float bias = bih[o] + (o < 512 ? bhh[o] : 0.0f);   // fold b_hh for r,z gates (n gate needs it inside r*hn)
    ushort4 st;
    st.x = f2bf(acc[0] + bias); st.y = f2bf(acc[1] + bias);
    st.z = f2bf(acc[2] + bias); st.w = f2bf(acc[3] + bias);
    *(ushort4*)(xp + ((size_t)(s * 768 + o) * 16 + b0)) = st;
  }
}

// ---------- stage 2: GRU, single workgroup, weights resident ----------
__global__ __launch_bounds__(512) void k_gru(const float* __restrict__ Whh,
    const float* __restrict__ bhh, const unsigned short* __restrict__ xp,
    unsigned short* __restrict__ hs) {
  extern __shared__ char smem[];
  unsigned short* w67 = (unsigned short*)smem;           // [768][72] bf16, K-tiles 6,7 (k=192..255)
  char* hb = smem + 768 * 72 * 2;                        // 2 x 8192 B: h (bf16) double-buffer, XOR-swizzled
  int tid = threadIdx.x;
  for (int e4 = tid; e4 < 768 * 64 / 4; e4 += 512) {
    int idx = e4 * 4;
    int n = idx >> 6, k = idx & 63;
    const float* p = Whh + n * 256 + 192 + k;
    float4 v = *(const float4*)p;
    ushort4 st; st.x = f2bf(v.x); st.y = f2bf(v.y); st.z = f2bf(v.z); st.w = f2bf(v.w);
    *(ushort4*)&w67[n * 72 + k] = st;
  }
  for (int e = tid; e < 1024; e += 512) {                // zero both h buffers (16 KB)
    uint4 z; z.x = z.y = z.z = z.w = 0u;
    ((uint4*)hb)[e] = z;
  }
  int lane = tid & 63, wv = tid >> 6;
  int col = lane & 15, krow = lane >> 4;
  int kh = krow * 8, b0 = krow * 4;
  // W_hh B-frags, K-tiles 0..5, in registers (36 frags = 144 VGPR)
  bf16x8 Wf[3][2][6];
#pragma unroll
  for (int g = 0; g < 3; ++g)
#pragma unroll
    for (int ut = 0; ut < 2; ++ut)
#pragma unroll
      for (int kk = 0; kk < 6; ++kk) {
        int n = g * 256 + wv * 32 + ut * 16 + col;
        const float* p = Whh + n * 256 + kk * 32 + kh;
        float4 f0 = *(const float4*)p;
        float4 f1 = *(const float4*)(p + 4);
        bf16x8 a;
        a[0] = (short)f2bf(f0.x); a[1] = (short)f2bf(f0.y);
        a[2] = (short)f2bf(f0.z); a[3] = (short)f2bf(f0.w);
        a[4] = (short)f2bf(f1.x); a[5] = (short)f2bf(f1.y);
        a[6] = (short)f2bf(f1.z); a[7] = (short)f2bf(f1.w);
        Wf[g][ut][kk] = a;
      }
  float bhn[2];
  int xoff[3][2], wboff[3][2];
#pragma unroll
  for (int g = 0; g < 3; ++g)
#pragma unroll
    for (int ut = 0; ut < 2; ++ut) {
      int o = g * 256 + wv * 32 + ut * 16 + col;
      xoff[g][ut]  = o * 16 + b0;
      wboff[g][ut] = o * 72 + kh;
      if (g == 2) bhn[ut] = bhh[o];
    }
  int swz = (col & 7) << 4;
  int aoff[8];
#pragma unroll
  for (int kk = 0; kk < 8; ++kk)
    aoff[kk] = col * 512 + ((((kk << 6) | (kh << 1))) ^ swz);
  unsigned raw = (unsigned)tid * 16u;                    // hs-copy: raw 16B slot per thread
  unsigned cb = raw >> 9;
  unsigned hsdst = cb * 256 + (((raw & 511u) ^ ((cb & 7u) << 4)) >> 1);
  int goff[2][4];
#pragma unroll
  for (int ut = 0; ut < 2; ++ut)
#pragma unroll
    for (int j = 0; j < 4; ++j) {
      int u = wv * 32 + ut * 16 + col;
      int b = b0 + j;
      goff[ut][j] = b * 512 + (((u << 1)) ^ ((b & 7) << 4));
    }
  float hreg[2][4] = {{0.f,0.f,0.f,0.f},{0.f,0.f,0.f,0.f}};
  ushort4 xc[3][2];
#pragma unroll
  for (int g = 0; g < 3; ++g)
#pragma unroll
    for (int ut = 0; ut < 2; ++ut)
      xc[g][ut] = *(const ushort4*)(xp + xoff[g][ut]);
  __syncthreads();

  for (int s = 0; s < NS; ++s) {
    const char* cur = hb + (s & 1) * 8192;
    char* nxt = hb + ((s & 1) ^ 1) * 8192;
    f32x4 acc[3][2];
    f32x4 z4 = {0.f, 0.f, 0.f, 0.f};
#pragma unroll
    for (int g = 0; g < 3; ++g)
#pragma unroll
      for (int ut = 0; ut < 2; ++ut) acc[g][ut] = z4;
#pragma unroll
    for (int kk = 0; kk < 8; ++kk) {
      bf16x8 a = *(const bf16x8*)(cur + aoff[kk]);
#pragma unroll
      for (int g = 0; g < 3; ++g)
#pragma unroll
        for (int ut = 0; ut < 2; ++ut) {
          bf16x8 bw;
          if (kk < 6) bw = Wf[g][ut][kk];
          else        bw = *(const bf16x8*)&w67[wboff[g][ut] + (kk - 6) * 32];
          acc[g][ut] = MFMA16(a, bw, acc[g][ut]);
        }
    }
    if (s > 0) {                                          // stream h_{s-1} -> hs[s-1][b][u] (bf16)
      uint4 v = *(const uint4*)(cur + raw);
      *(uint4*)(hs + (size_t)(s - 1) * 4096 + hsdst) = v;
    }
    int sp = (s + 1 < NS) ? (s + 1) : (NS - 1);           // prefetch next-step gate inputs
    const unsigned short* xpp = xp + (size_t)sp * 12288;
    ushort4 xn_[3][2];
#pragma unroll
    for (int g = 0; g < 3; ++g)
#pragma unroll
      for (int ut = 0; ut < 2; ++ut)
        xn_[g][ut] = *(const ushort4*)(xpp + xoff[g][ut]);
#pragma unroll
    for (int ut = 0; ut < 2; ++ut) {
#pragma unroll
      for (int j = 0; j < 4; ++j) {
        unsigned short xrj = (j==0)?xc[0][ut].x:(j==1)?xc[0][ut].y:(j==2)?xc[0][ut].z:xc[0][ut].w;
        unsigned short xzj = (j==0)?xc[1][ut].x:(j==1)?xc[1][ut].y:(j==2)?xc[1][ut].z:xc[1][ut].w;
        unsigned short xnj = (j==0)?xc[2][ut].x:(j==1)?xc[2][ut].y:(j==2)?xc[2][ut].z:xc[2][ut].w;
        float r  = fsig(bf2f(xrj) + acc[0][ut][j]);
        float z  = fsig(bf2f(xzj) + acc[1][ut][j]);
        float nn = ftanh(fmaf(r, acc[2][ut][j] + bhn[ut], bf2f(xnj)));
        float h  = hreg[ut][j];
        h = fmaf(z, h - nn, nn);
        hreg[ut][j] = h;
        *(unsigned short*)(nxt + goff[ut][j]) = f2bf(h);
      }
    }
#pragma unroll
    for (int g = 0; g < 3; ++g)
#pragma unroll
      for (int ut = 0; ut < 2; ++ut) xc[g][ut] = xn_[g][ut];
    __syncthreads();
  }
  {                                                       // final h_{NS-1}
    const char* cur = hb + (NS & 1) * 8192;
    uint4 v = *(const uint4*)(cur + raw);
    *(uint4*)(hs + (size_t)(NS - 1) * 4096 + hsdst) = v;
  }
}

// ---------- stage 3: eps = hs @ W_proj.T + b_proj; A=sigmoid(first 128); Ag[s][b][256] fp32 ----------
__global__ __launch_bounds__(256) void k_eps(const unsigned short* __restrict__ hs,
    const float* __restrict__ Wp, const float* __restrict__ bp,
    float* __restrict__ Ag) {
  extern __shared__ char smem[];
  unsigned short* wl = (unsigned short*)smem;             // [256][264] bf16
  for (int e4 = threadIdx.x; e4 < 256 * 256 / 4; e4 += 256) {
    int idx = e4 * 4;
    int o = idx >> 8, k = idx & 255;
    float4 v = ((const float4*)Wp)[e4];
    ushort4 st; st.x = f2bf(v.x); st.y = f2bf(v.y); st.z = f2bf(v.z); st.w = f2bf(v.w);
    *(ushort4*)&wl[o * 264 + k] = st;
  }
  __syncthreads();
  int lane = threadIdx.x & 63;
  int s = blockIdx.x * 4 + (threadIdx.x >> 6);
  if (s >= NS) return;
  int col = lane & 15, krow = lane >> 4;
  int kh = krow * 8, b0 = krow * 4;
  bf16x8 A[8];
#pragma unroll
  for (int kk = 0; kk < 8; ++kk)
    A[kk] = *(const bf16x8*)(hs + (size_t)s * 4096 + col * 256 + kk * 32 + kh);
#pragma unroll 4
  for (int n = 0; n < 16; ++n) {
    f32x4 acc = {0.f, 0.f, 0.f, 0.f};
#pragma unroll
    for (int kk = 0; kk < 8; ++kk) {
      bf16x8 bw = *(const bf16x8*)&wl[(n * 16 + col) * 264 + kk * 32 + kh];
      acc = MFMA16(A[kk], bw, acc);
    }
    int o = n * 16 + col;
    float bias = bp[o];
#pragma unroll
    for (int j = 0; j < 4; ++j) {
      float v = acc[j] + bias;
      if (n < 8) v = fsig(v);                             // A half (o<128)
      Ag[(size_t)(s * 16 + b0 + j) * 256 + o] = v;
    }
  }
}

// ---------- stage 4: fast SSM scan + overlap-add ----------
__global__ __launch_bounds__(256) void k_ssm(const float* __restrict__ x,
    const float* __restrict__ Ag, const float* __restrict__ Win,
    const float* __restrict__ Wout, const float* __restrict__ Dp,
    float* __restrict__ out) {
  int tid = threadIdx.x, lane = tid & 63;
  int wid = blockIdx.x * 4 + (tid >> 6);
  if (wid >= BB * NF) return;
  int b = wid / NF, i = wid - b * NF;
  int sidx = i / 3 - 1; if (sidx < 0) sidx = 0;
  const float* ag = Ag + (size_t)(sidx * 16 + b) * 256;
  float2 A2 = *(const float2*)(ag + 2 * lane);
  float2 g2 = *(const float2*)(ag + 128 + 2 * lane);
  float2 wi = *(const float2*)(Win + 2 * lane);
  float2 wo = *(const float2*)(Wout + 2 * lane);
  float gw0 = g2.x * wo.x, gw1 = g2.y * wo.y;
  float Dv = Dp[0];
  float xv = x[(size_t)b * TT + i * 16 + (lane & 31)];
  float h0 = 0.f, h1 = 0.f;
  float* ob = out + (size_t)b * TT + i * 16;
#pragma unroll
  for (int t = 0; t < 32; ++t) {
    float xt = __shfl(xv, t, 64);
    h0 = fmaf(A2.x, h0, xt * wi.x);
    h1 = fmaf(A2.y, h1, xt * wi.y);
    float c = fmaf(h0, gw0, h1 * gw1);
    c += __shfl_xor(c, 1, 64);
    c += __shfl_xor(c, 2, 64);
    c += __shfl_xor(c, 4, 64);
    c += __shfl_xor(c, 8, 64);
    c += __shfl_xor(c, 16, 64);
    c += __shfl_xor(c, 32, 64);
    if (lane == 0) atomicAdd(&ob[t], fmaf(Dv, xt, c));
  }
}

extern "C" void kernel_launch(void* const* d_in, const int* in_sizes, int n_in,
                              void* d_out, int out_size, void* d_ws, size_t ws_size,
                              hipStream_t stream) {
  const float* x     = (const float*)d_in[0];
  const float* Wih   = (const float*)d_in[1];
  const float* Whh   = (const float*)d_in[2];
  const float* bih   = (const float*)d_in[3];
  const float* bhh   = (const float*)d_in[4];
  const float* Wproj = (const float*)d_in[5];
  const float* bproj = (const float*)d_in[6];
  const float* Win   = (const float*)d_in[7];
  const float* Wout  = (const float*)d_in[8];
  const float* Dp    = (const float*)d_in[9];
  float* out = (float*)d_out;

  char* ws = (char*)d_ws;
  unsigned short* xp = (unsigned short*)ws;                           // [NS][768][16] bf16 = 33,546,240 B
  unsigned short* hs = (unsigned short*)(ws + 33546240);              // [NS][16][256] bf16 = 11,182,080 B
  float*          Ag = (float*)(ws + 33546240 + 11182080);            // [NS][16][256] f32  = 22,364,160 B

  const int lds_xproj = 768 * 104 * 2;            // 159,744
  const int lds_gru   = 768 * 72 * 2 + 16384;     // 126,976
  const int lds_eps   = 256 * 264 * 2;            // 135,168
  hipFuncSetAttribute((const void*)k_xproj, hipFuncAttributeMaxDynamicSharedMemorySize, lds_xproj);
  hipFuncSetAttribute((const void*)k_gru,   hipFuncAttributeMaxDynamicSharedMemorySize, lds_gru);
  hipFuncSetAttribute((const void*)k_eps,   hipFuncAttributeMaxDynamicSharedMemorySize, lds_eps);

  hipMemsetAsync(d_out, 0, (size_t)out_size * sizeof(float), stream);
  hipLaunchKernelGGL(k_xproj, dim3(342), dim3(256), lds_xproj, stream, x, Wih, bih, bhh, xp);
  hipLaunchKernelGGL(k_gru,   dim3(1),   dim3(512), lds_gru,   stream, Whh, bhh, xp, hs);
  hipLaunchKernelGGL(k_eps,   dim3(342), dim3(256), lds_eps,   stream, hs, Wproj, bproj, Ag);
  hipLaunchKernelGGL(k_ssm,   dim3(16388), dim3(256), 0, stream, x, Ag, Win, Wout, Dp, out);
}